// Round 4
// baseline (135.236 us; speedup 1.0000x reference)
//
#include <hip/hip_runtime.h>

#define LN_EPS 1e-5f

typedef __attribute__((ext_vector_type(8))) short s16x8;
typedef __attribute__((ext_vector_type(4))) float f32x4;

__device__ inline unsigned int pk_bf16(float a, float b) {
    unsigned ua = __builtin_bit_cast(unsigned, a);
    unsigned ub = __builtin_bit_cast(unsigned, b);
    ua += 0x7fffu + ((ua >> 16) & 1u);
    ub += 0x7fffu + ((ub >> 16) & 1u);
    return (ua >> 16) | (ub & 0xffff0000u);
}

__device__ inline void gl_lds16(const void* g, void* l) {
    __builtin_amdgcn_global_load_lds((const __attribute__((address_space(1))) void*)g,
                                     (__attribute__((address_space(3))) void*)l, 16, 0, 0);
}

// ---------------- K1: degree pass + masked bf16 adjacency ----------------
__global__ __launch_bounds__(256) void k_deg(const float* __restrict__ adj,
                                             const int* __restrict__ pm,
                                             const float* __restrict__ ew,
                                             float* __restrict__ dis_o,
                                             float* __restrict__ rs,
                                             float* __restrict__ rself,
                                             unsigned short* __restrict__ am,
                                             int L) {
    int row = blockIdx.x;
    int b = row / L;
    int i = row - b * L;
    const float* arow = adj + (size_t)row * L;
    const int* pmb = pm + (size_t)b * L;
    unsigned short* amrow = am + (size_t)row * L;
    int t = threadIdx.x;
    float validi = (pmb[i] == 0) ? 1.f : 0.f;
    float s = 0.f;
    for (int j0 = t * 8; j0 < L; j0 += 2048) {
        float4 a0 = *(const float4*)(arow + j0);
        float4 a1 = *(const float4*)(arow + j0 + 4);
        int4 p0 = *(const int4*)(pmb + j0);
        int4 p1 = *(const int4*)(pmb + j0 + 4);
        float m0 = p0.x == 0 ? a0.x : 0.f;
        float m1 = p0.y == 0 ? a0.y : 0.f;
        float m2 = p0.z == 0 ? a0.z : 0.f;
        float m3 = p0.w == 0 ? a0.w : 0.f;
        float m4 = p1.x == 0 ? a1.x : 0.f;
        float m5 = p1.y == 0 ? a1.y : 0.f;
        float m6 = p1.z == 0 ? a1.z : 0.f;
        float m7 = p1.w == 0 ? a1.w : 0.f;
        s += ((m0 + m1) + (m2 + m3)) + ((m4 + m5) + (m6 + m7));
        uint4 o;
        o.x = pk_bf16(validi * m0, validi * m1);
        o.y = pk_bf16(validi * m2, validi * m3);
        o.z = pk_bf16(validi * m4, validi * m5);
        o.w = pk_bf16(validi * m6, validi * m7);
        *(uint4*)(amrow + j0) = o;
    }
    #pragma unroll
    for (int off = 32; off; off >>= 1) s += __shfl_down(s, off);
    __shared__ float wsum[4];
    if ((t & 63) == 0) wsum[t >> 6] = s;
    __syncthreads();
    if (t == 0) {
        float tot = wsum[0] + wsum[1] + wsum[2] + wsum[3];
        float deg = 1.f + validi * tot;   // >= 1 (self-loop)
        float d = rsqrtf(deg);
        float e = ew[0];
        dis_o[row]  = d;
        rs[row]     = e * validi * d;
        rself[row]  = e * d * d;
    }
}

// ---------------- K2: transpose + scale + convert: yht[b,d,l] = bf16(dis_l * x[b,l,d]) ----------------
__global__ __launch_bounds__(256) void k_xt(const float* __restrict__ x,
                                            const float* __restrict__ dis,
                                            unsigned short* __restrict__ yht,
                                            int L, int D) {
    __shared__ float tile[64][65];
    int l0 = blockIdx.x << 6, d0 = blockIdx.y << 6, b = blockIdx.z;
    int t = threadIdx.x;
    int lr = t >> 2, c4 = (t & 3) << 4;
    float dl = dis[(size_t)b * L + l0 + lr];
    const float* xp = x + ((size_t)b * L + l0 + lr) * D + d0 + c4;
    #pragma unroll
    for (int k = 0; k < 16; k += 4) {
        float4 v = *(const float4*)(xp + k);
        tile[lr][c4 + k + 0] = v.x * dl;
        tile[lr][c4 + k + 1] = v.y * dl;
        tile[lr][c4 + k + 2] = v.z * dl;
        tile[lr][c4 + k + 3] = v.w * dl;
    }
    __syncthreads();
    int dr = t >> 2, k0 = (t & 3) << 4;
    unsigned short* op = yht + ((size_t)b * D + d0 + dr) * L + l0 + k0;
    uint4 o0, o1;
    o0.x = pk_bf16(tile[k0 + 0][dr],  tile[k0 + 1][dr]);
    o0.y = pk_bf16(tile[k0 + 2][dr],  tile[k0 + 3][dr]);
    o0.z = pk_bf16(tile[k0 + 4][dr],  tile[k0 + 5][dr]);
    o0.w = pk_bf16(tile[k0 + 6][dr],  tile[k0 + 7][dr]);
    o1.x = pk_bf16(tile[k0 + 8][dr],  tile[k0 + 9][dr]);
    o1.y = pk_bf16(tile[k0 + 10][dr], tile[k0 + 11][dr]);
    o1.z = pk_bf16(tile[k0 + 12][dr], tile[k0 + 13][dr]);
    o1.w = pk_bf16(tile[k0 + 14][dr], tile[k0 + 15][dr]);
    *(uint4*)(op) = o0;
    *(uint4*)(op + 8) = o1;
}

// ---------------- K2b: W -> bf16 ----------------
__global__ __launch_bounds__(256) void k_wh(const float* __restrict__ W,
                                            unsigned short* __restrict__ Wh) {
    int i = (blockIdx.x * 256 + threadIdx.x) * 4;
    float4 v = *(const float4*)(W + i);
    uint2 o;
    o.x = pk_bf16(v.x, v.y);
    o.y = pk_bf16(v.z, v.w);
    *(uint2*)(Wh + i) = o;
}

// ---------------- K3: agg = rs_i * (am @ y) + rself_i * x  (MFMA bf16, dbuf 2-phase) ----------------
// BM=BN=128, BK=64; 4 waves of 64x64; double-buffered LDS, stage-ahead.
__global__ __launch_bounds__(256, 2) void k_aggmm(
    const unsigned short* __restrict__ am,
    const unsigned short* __restrict__ yht,
    const float* __restrict__ x,
    const float* __restrict__ rs,
    const float* __restrict__ rself,
    unsigned short* __restrict__ aggh,
    int L, int D)
{
    __shared__ __align__(16) unsigned short As[2][128 * 64];
    __shared__ __align__(16) unsigned short Bs[2][128 * 64];
    int bid = blockIdx.x;
    int wid = (bid & 7) * 64 + (bid >> 3);   // one batch per XCD (512 = 8*64, bijective)
    int b   = wid >> 6;
    int t6  = wid & 63;
    int brow = (t6 >> 2) << 7;
    int bcol = (t6 & 3) << 7;

    int t = threadIdx.x;
    int lane = t & 63;
    int w = t >> 6;
    int wr = ((w >> 1) & 1) << 6;
    int wc = (w & 1) << 6;

    const unsigned short* amb = am + ((size_t)b * L + brow) * L;
    const unsigned short* yb  = yht + ((size_t)b * D + bcol) * L;

    int srow = t >> 3;          // 0..31
    int chunk = t & 7;

    f32x4 acc[4][4];
    #pragma unroll
    for (int i = 0; i < 4; ++i)
        #pragma unroll
        for (int j = 0; j < 4; ++j)
            acc[i][j] = (f32x4){0.f, 0.f, 0.f, 0.f};

    const int lane15 = lane & 15;
    const int kbyte = (lane >> 4) << 4;
    const int swa = (lane & 7) << 4;

    // prologue stage tile 0
    {
        char* Ad = (char*)As[0];
        char* Bd = (char*)Bs[0];
        #pragma unroll
        for (int q = 0; q < 4; ++q) {
            int row = srow + (q << 5);
            int sc = chunk ^ (row & 7);      // pre-swizzled global source, linear LDS dest
            gl_lds16(amb + (size_t)row * L + sc * 8, Ad + row * 128 + chunk * 16);
            gl_lds16(yb  + (size_t)row * L + sc * 8, Bd + row * 128 + chunk * 16);
        }
    }
    asm volatile("s_waitcnt vmcnt(0)" ::: "memory");
    __syncthreads();

    int cur = 0;
    for (int kc = 0; kc < L; kc += 64) {
        if (kc + 64 < L) {                   // stage next tile into other buffer
            char* Ad = (char*)As[cur ^ 1];
            char* Bd = (char*)Bs[cur ^ 1];
            #pragma unroll
            for (int q = 0; q < 4; ++q) {
                int row = srow + (q << 5);
                int sc = chunk ^ (row & 7);
                gl_lds16(amb + (size_t)row * L + kc + 64 + sc * 8, Ad + row * 128 + chunk * 16);
                gl_lds16(yb  + (size_t)row * L + kc + 64 + sc * 8, Bd + row * 128 + chunk * 16);
            }
        }
        const char* Ac = (const char*)As[cur];
        const char* Bc = (const char*)Bs[cur];
        #pragma unroll
        for (int kk = 0; kk < 2; ++kk) {
            s16x8 af[4], bg[4];
            #pragma unroll
            for (int f = 0; f < 4; ++f) {
                int ar = wr + (f << 4) + lane15;
                af[f] = *(const s16x8*)(Ac + ar * 128 + (((kk << 6) + kbyte) ^ swa));
                int br = wc + (f << 4) + lane15;
                bg[f] = *(const s16x8*)(Bc + br * 128 + (((kk << 6) + kbyte) ^ swa));
            }
            #pragma unroll
            for (int fm = 0; fm < 4; ++fm)
                #pragma unroll
                for (int fn = 0; fn < 4; ++fn)
                    acc[fm][fn] = __builtin_amdgcn_mfma_f32_16x16x32_bf16(af[fm], bg[fn], acc[fm][fn], 0, 0, 0);
        }
        asm volatile("s_waitcnt vmcnt(0)" ::: "memory");
        __syncthreads();
        cur ^= 1;
    }

    int col = lane15;
    int r0 = (lane >> 4) << 2;
    size_t bL = (size_t)b * L;
    #pragma unroll
    for (int fm = 0; fm < 4; ++fm) {
        #pragma unroll
        for (int j = 0; j < 4; ++j) {
            int gi = brow + wr + (fm << 4) + r0 + j;
            float rsi = rs[bL + gi];
            float rfi = rself[bL + gi];
            const float* xrow = x + (bL + gi) * (size_t)D;
            unsigned short* orow = aggh + (bL + gi) * (size_t)D;
            #pragma unroll
            for (int fn = 0; fn < 4; ++fn) {
                int gd = bcol + wc + (fn << 4) + col;
                float v = rsi * acc[fm][fn][j] + rfi * xrow[gd];
                unsigned ua = __builtin_bit_cast(unsigned, v);
                ua += 0x7fffu + ((ua >> 16) & 1u);
                orow[gd] = (unsigned short)(ua >> 16);
            }
        }
    }
}

// ---------------- K4: out = LN(x + relu(agg @ W^T + b) * D^-0.5) ----------------
// LDS-free GEMM: fragments loaded direct from global (Wh + 32-row aggh tile are L1/L2 resident).
__global__ __launch_bounds__(256, 2) void k_linln(
    const unsigned short* __restrict__ aggh,
    const unsigned short* __restrict__ Wh,
    const float* __restrict__ bias,
    const float* __restrict__ x,
    const float* __restrict__ lnw,
    const float* __restrict__ lnb,
    float* __restrict__ out)
{
    const int D = 512;
    __shared__ float psum[32][4], psq[32][4];

    int i0 = blockIdx.x << 5;
    int t = threadIdx.x;
    int lane = t & 63;
    int w = t >> 6;
    int wc = w << 7;                 // wave column base (0,128,256,384)
    const int lane15 = lane & 15;
    const int k8 = (lane >> 4) << 3; // element offset of this lane's 16B k-chunk

    const unsigned short* abase = aggh + (size_t)(i0 + lane15) * D + k8;
    const unsigned short* bbase = Wh + (size_t)(wc + lane15) * D + k8;

    f32x4 acc[2][8];
    #pragma unroll
    for (int i = 0; i < 2; ++i)
        #pragma unroll
        for (int j = 0; j < 8; ++j)
            acc[i][j] = (f32x4){0.f, 0.f, 0.f, 0.f};

    for (int kc = 0; kc < D; kc += 64) {
        #pragma unroll
        for (int kk = 0; kk < 2; ++kk) {
            int ko = kc + (kk << 5);
            s16x8 af[2], bg[8];
            #pragma unroll
            for (int f = 0; f < 2; ++f)
                af[f] = *(const s16x8*)(abase + (size_t)(f << 4) * D + ko);
            #pragma unroll
            for (int f = 0; f < 8; ++f)
                bg[f] = *(const s16x8*)(bbase + (size_t)(f << 4) * D + ko);
            #pragma unroll
            for (int fm = 0; fm < 2; ++fm)
                #pragma unroll
                for (int fn = 0; fn < 8; ++fn)
                    acc[fm][fn] = __builtin_amdgcn_mfma_f32_16x16x32_bf16(af[fm], bg[fn], acc[fm][fn], 0, 0, 0);
        }
    }

    // epilogue: h = x + relu(acc + b)*scale, then LN over full rows
    const float scale = 0.044194173824159216f;   // 512^-0.5
    float bi[8], lw[8], lb[8];
    #pragma unroll
    for (int fn = 0; fn < 8; ++fn) {
        int colg = wc + (fn << 4) + lane15;
        bi[fn] = bias[colg];
        lw[fn] = lnw[colg];
        lb[fn] = lnb[colg];
    }
    int r0 = (lane >> 4) << 2;
    #pragma unroll
    for (int fm = 0; fm < 2; ++fm) {
        #pragma unroll
        for (int j = 0; j < 4; ++j) {
            int r = (fm << 4) + r0 + j;
            const float* xrow = x + (size_t)(i0 + r) * D;
            float s = 0.f, q = 0.f;
            #pragma unroll
            for (int fn = 0; fn < 8; ++fn) {
                int colg = wc + (fn << 4) + lane15;
                float v = fmaxf(acc[fm][fn][j] + bi[fn], 0.f) * scale + xrow[colg];
                acc[fm][fn][j] = v;
                s += v;
                q += v * v;
            }
            #pragma unroll
            for (int m = 1; m < 16; m <<= 1) {
                s += __shfl_xor(s, m);
                q += __shfl_xor(q, m);
            }
            if (lane15 == 0) { psum[r][w] = s; psq[r][w] = q; }
        }
    }
    __syncthreads();
    #pragma unroll
    for (int fm = 0; fm < 2; ++fm) {
        #pragma unroll
        for (int j = 0; j < 4; ++j) {
            int r = (fm << 4) + r0 + j;
            float s = psum[r][0] + psum[r][1] + psum[r][2] + psum[r][3];
            float q = psq[r][0] + psq[r][1] + psq[r][2] + psq[r][3];
            float mu = s * (1.f / 512.f);
            float var = q * (1.f / 512.f) - mu * mu;
            float rstd = rsqrtf(var + LN_EPS);
            float* orow = out + (size_t)(i0 + r) * D;
            #pragma unroll
            for (int fn = 0; fn < 8; ++fn) {
                int colg = wc + (fn << 4) + lane15;
                orow[colg] = lw[fn] * (acc[fm][fn][j] - mu) * rstd + lb[fn];
            }
        }
    }
}

extern "C" void kernel_launch(void* const* d_in, const int* in_sizes, int n_in,
                              void* d_out, int out_size, void* d_ws, size_t ws_size,
                              hipStream_t stream) {
    const float* x    = (const float*)d_in[0];
    const float* adj  = (const float*)d_in[1];
    const int*   pm   = (const int*)d_in[2];
    const float* W    = (const float*)d_in[3];
    const float* bias = (const float*)d_in[4];
    const float* lnw  = (const float*)d_in[5];
    const float* lnb  = (const float*)d_in[6];
    const float* ew   = (const float*)d_in[7];

    int BL = in_sizes[2];                 // B*L = 16384
    int L  = in_sizes[1] / BL;            // 2048
    int B  = BL / L;                      // 8
    int D  = in_sizes[0] / BL;            // 512

    char* ws = (char*)d_ws;
    size_t off = 0;
    float* dis   = (float*)(ws + off); off += (size_t)BL * 4;
    float* rs    = (float*)(ws + off); off += (size_t)BL * 4;
    float* rself = (float*)(ws + off); off += (size_t)BL * 4;
    unsigned short* am   = (unsigned short*)(ws + off); off += (size_t)BL * L * 2;
    unsigned short* yht  = (unsigned short*)(ws + off); off += (size_t)BL * D * 2;
    unsigned short* Wh   = (unsigned short*)(ws + off); off += (size_t)D * D * 2;
    unsigned short* aggh = (unsigned short*)(ws + off); off += (size_t)BL * D * 2;

    float* out = (float*)d_out;

    k_deg<<<BL, 256, 0, stream>>>(adj, pm, ew, dis, rs, rself, am, L);
    k_wh<<<(D * D) / 1024, 256, 0, stream>>>(W, Wh);
    k_xt<<<dim3(L / 64, D / 64, B), 256, 0, stream>>>(x, dis, yht, L, D);
    k_aggmm<<<B * (L / 128) * (D / 128), 256, 0, stream>>>(am, yht, x, rs, rself, aggh, L, D);
    k_linln<<<BL / 32, 256, 0, stream>>>(aggh, Wh, bias, x, lnw, lnb, out);
}

// Round 5
// 113.931 us; speedup vs baseline: 1.1870x; 1.1870x over previous
//
#include <hip/hip_runtime.h>

#define LN_EPS 1e-5f

typedef __attribute__((ext_vector_type(8))) short s16x8;
typedef __attribute__((ext_vector_type(4))) float f32x4;

__device__ inline unsigned int pk_bf16(float a, float b) {
    unsigned ua = __builtin_bit_cast(unsigned, a);
    unsigned ub = __builtin_bit_cast(unsigned, b);
    ua += 0x7fffu + ((ua >> 16) & 1u);
    ub += 0x7fffu + ((ub >> 16) & 1u);
    return (ua >> 16) | (ub & 0xffff0000u);
}

__device__ inline void gl_lds16(const void* g, void* l) {
    __builtin_amdgcn_global_load_lds((const __attribute__((address_space(1))) void*)g,
                                     (__attribute__((address_space(3))) void*)l, 16, 0, 0);
}

// ---------------- K1: degree pass + masked bf16 adjacency ----------------
__global__ __launch_bounds__(256) void k_deg(const float* __restrict__ adj,
                                             const int* __restrict__ pm,
                                             const float* __restrict__ ew,
                                             float* __restrict__ dis_o,
                                             float* __restrict__ rs,
                                             float* __restrict__ rself,
                                             unsigned short* __restrict__ am,
                                             int L) {
    int row = blockIdx.x;
    int b = row / L;
    int i = row - b * L;
    const float* arow = adj + (size_t)row * L;
    const int* pmb = pm + (size_t)b * L;
    unsigned short* amrow = am + (size_t)row * L;
    int t = threadIdx.x;
    float validi = (pmb[i] == 0) ? 1.f : 0.f;
    float s = 0.f;
    for (int j0 = t * 8; j0 < L; j0 += 2048) {
        float4 a0 = *(const float4*)(arow + j0);
        float4 a1 = *(const float4*)(arow + j0 + 4);
        int4 p0 = *(const int4*)(pmb + j0);
        int4 p1 = *(const int4*)(pmb + j0 + 4);
        float m0 = p0.x == 0 ? a0.x : 0.f;
        float m1 = p0.y == 0 ? a0.y : 0.f;
        float m2 = p0.z == 0 ? a0.z : 0.f;
        float m3 = p0.w == 0 ? a0.w : 0.f;
        float m4 = p1.x == 0 ? a1.x : 0.f;
        float m5 = p1.y == 0 ? a1.y : 0.f;
        float m6 = p1.z == 0 ? a1.z : 0.f;
        float m7 = p1.w == 0 ? a1.w : 0.f;
        s += ((m0 + m1) + (m2 + m3)) + ((m4 + m5) + (m6 + m7));
        uint4 o;
        o.x = pk_bf16(validi * m0, validi * m1);
        o.y = pk_bf16(validi * m2, validi * m3);
        o.z = pk_bf16(validi * m4, validi * m5);
        o.w = pk_bf16(validi * m6, validi * m7);
        *(uint4*)(amrow + j0) = o;
    }
    #pragma unroll
    for (int off = 32; off; off >>= 1) s += __shfl_down(s, off);
    __shared__ float wsum[4];
    if ((t & 63) == 0) wsum[t >> 6] = s;
    __syncthreads();
    if (t == 0) {
        float tot = wsum[0] + wsum[1] + wsum[2] + wsum[3];
        float deg = 1.f + validi * tot;   // >= 1 (self-loop)
        float d = rsqrtf(deg);
        float e = ew[0];
        dis_o[row]  = d;
        rs[row]     = e * validi * d;
        rself[row]  = e * d * d;
    }
}

// ---------------- K2: transpose + scale + convert: yht[b,d,l] = bf16(dis_l * x[b,l,d]) ----------------
__global__ __launch_bounds__(256) void k_xt(const float* __restrict__ x,
                                            const float* __restrict__ dis,
                                            unsigned short* __restrict__ yht,
                                            int L, int D) {
    __shared__ float tile[64][65];
    int l0 = blockIdx.x << 6, d0 = blockIdx.y << 6, b = blockIdx.z;
    int t = threadIdx.x;
    int lr = t >> 2, c4 = (t & 3) << 4;
    float dl = dis[(size_t)b * L + l0 + lr];
    const float* xp = x + ((size_t)b * L + l0 + lr) * D + d0 + c4;
    #pragma unroll
    for (int k = 0; k < 16; k += 4) {
        float4 v = *(const float4*)(xp + k);
        tile[lr][c4 + k + 0] = v.x * dl;
        tile[lr][c4 + k + 1] = v.y * dl;
        tile[lr][c4 + k + 2] = v.z * dl;
        tile[lr][c4 + k + 3] = v.w * dl;
    }
    __syncthreads();
    int dr = t >> 2, k0 = (t & 3) << 4;
    unsigned short* op = yht + ((size_t)b * D + d0 + dr) * L + l0 + k0;
    uint4 o0, o1;
    o0.x = pk_bf16(tile[k0 + 0][dr],  tile[k0 + 1][dr]);
    o0.y = pk_bf16(tile[k0 + 2][dr],  tile[k0 + 3][dr]);
    o0.z = pk_bf16(tile[k0 + 4][dr],  tile[k0 + 5][dr]);
    o0.w = pk_bf16(tile[k0 + 6][dr],  tile[k0 + 7][dr]);
    o1.x = pk_bf16(tile[k0 + 8][dr],  tile[k0 + 9][dr]);
    o1.y = pk_bf16(tile[k0 + 10][dr], tile[k0 + 11][dr]);
    o1.z = pk_bf16(tile[k0 + 12][dr], tile[k0 + 13][dr]);
    o1.w = pk_bf16(tile[k0 + 14][dr], tile[k0 + 15][dr]);
    *(uint4*)(op) = o0;
    *(uint4*)(op + 8) = o1;
}

// ---------------- K2b: W -> bf16 ----------------
__global__ __launch_bounds__(256) void k_wh(const float* __restrict__ W,
                                            unsigned short* __restrict__ Wh) {
    int i = (blockIdx.x * 256 + threadIdx.x) * 4;
    float4 v = *(const float4*)(W + i);
    uint2 o;
    o.x = pk_bf16(v.x, v.y);
    o.y = pk_bf16(v.z, v.w);
    *(uint2*)(Wh + i) = o;
}

// ---------------- K3: agg = rs_i * (am @ y) + rself_i * x ----------------
// MFMA bf16; BM=BN=128, BK=64; 4 waves of 64x64.
// Double-buffered with COUNTED vmcnt: tile t+1's 8 loads stay in flight
// across the barrier and tile t's MFMA phase (T3+T4).
__global__ __launch_bounds__(256, 2) void k_aggmm(
    const unsigned short* __restrict__ am,
    const unsigned short* __restrict__ yht,
    const float* __restrict__ x,
    const float* __restrict__ rs,
    const float* __restrict__ rself,
    unsigned short* __restrict__ aggh,
    int L, int D)
{
    __shared__ __align__(16) unsigned short As[2][128 * 64];
    __shared__ __align__(16) unsigned short Bs[2][128 * 64];
    int bid = blockIdx.x;
    int wid = (bid & 7) * 64 + (bid >> 3);   // one batch per XCD (512 = 8*64, bijective)
    int b   = wid >> 6;
    int t6  = wid & 63;
    int brow = (t6 >> 2) << 7;
    int bcol = (t6 & 3) << 7;

    int t = threadIdx.x;
    int lane = t & 63;
    int w = t >> 6;
    int wr = ((w >> 1) & 1) << 6;
    int wc = (w & 1) << 6;

    const unsigned short* amb = am + ((size_t)b * L + brow) * L;
    const unsigned short* yb  = yht + ((size_t)b * D + bcol) * L;

    int srow = t >> 3;          // 0..31
    int chunk = t & 7;

    f32x4 acc[4][4];
    #pragma unroll
    for (int i = 0; i < 4; ++i)
        #pragma unroll
        for (int j = 0; j < 4; ++j)
            acc[i][j] = (f32x4){0.f, 0.f, 0.f, 0.f};

    const int lane15 = lane & 15;
    const int kbyte = (lane >> 4) << 4;
    const int swa = (lane & 7) << 4;

    // prologue: stage tile 0 into buffer 0 (8 loads/thread in flight)
    {
        char* Ad = (char*)As[0];
        char* Bd = (char*)Bs[0];
        #pragma unroll
        for (int q = 0; q < 4; ++q) {
            int row = srow + (q << 5);
            int sc = chunk ^ (row & 7);      // pre-swizzled global source, linear LDS dest
            gl_lds16(amb + (size_t)row * L + sc * 8, Ad + row * 128 + chunk * 16);
            gl_lds16(yb  + (size_t)row * L + sc * 8, Bd + row * 128 + chunk * 16);
        }
    }

    int cur = 0;
    for (int kc = 0; kc < L; kc += 64) {
        if (kc + 64 < L) {
            // stage next tile (8 more loads; 16 outstanding, oldest 8 = tile t)
            char* Ad = (char*)As[cur ^ 1];
            char* Bd = (char*)Bs[cur ^ 1];
            #pragma unroll
            for (int q = 0; q < 4; ++q) {
                int row = srow + (q << 5);
                int sc = chunk ^ (row & 7);
                gl_lds16(amb + (size_t)row * L + kc + 64 + sc * 8, Ad + row * 128 + chunk * 16);
                gl_lds16(yb  + (size_t)row * L + kc + 64 + sc * 8, Bd + row * 128 + chunk * 16);
            }
            asm volatile("s_waitcnt vmcnt(8)" ::: "memory");   // wait tile t only
        } else {
            asm volatile("s_waitcnt vmcnt(0)" ::: "memory");   // final drain
        }
        __syncthreads();

        const char* Ac = (const char*)As[cur];
        const char* Bc = (const char*)Bs[cur];
        #pragma unroll
        for (int kk = 0; kk < 2; ++kk) {
            s16x8 af[4], bg[4];
            #pragma unroll
            for (int f = 0; f < 4; ++f) {
                int ar = wr + (f << 4) + lane15;
                af[f] = *(const s16x8*)(Ac + ar * 128 + (((kk << 6) + kbyte) ^ swa));
                int br = wc + (f << 4) + lane15;
                bg[f] = *(const s16x8*)(Bc + br * 128 + (((kk << 6) + kbyte) ^ swa));
            }
            #pragma unroll
            for (int fm = 0; fm < 4; ++fm)
                #pragma unroll
                for (int fn = 0; fn < 4; ++fn)
                    acc[fm][fn] = __builtin_amdgcn_mfma_f32_16x16x32_bf16(af[fm], bg[fn], acc[fm][fn], 0, 0, 0);
        }
        __syncthreads();   // all waves done with buf[cur] before it is re-staged
        cur ^= 1;
    }

    int col = lane15;
    int r0 = (lane >> 4) << 2;
    size_t bL = (size_t)b * L;
    #pragma unroll
    for (int fm = 0; fm < 4; ++fm) {
        #pragma unroll
        for (int j = 0; j < 4; ++j) {
            int gi = brow + wr + (fm << 4) + r0 + j;
            float rsi = rs[bL + gi];
            float rfi = rself[bL + gi];
            const float* xrow = x + (bL + gi) * (size_t)D;
            unsigned short* orow = aggh + (bL + gi) * (size_t)D;
            #pragma unroll
            for (int fn = 0; fn < 4; ++fn) {
                int gd = bcol + wc + (fn << 4) + col;
                float v = rsi * acc[fm][fn][j] + rfi * xrow[gd];
                unsigned ua = __builtin_bit_cast(unsigned, v);
                ua += 0x7fffu + ((ua >> 16) & 1u);
                orow[gd] = (unsigned short)(ua >> 16);
            }
        }
    }
}

// ---------------- K4: out = LN(x + relu(agg @ W^T + b) * D^-0.5)  (fused, BM=32 x BN=512) ----------------
__global__ __launch_bounds__(256, 2) void k_linln(
    const unsigned short* __restrict__ aggh,
    const unsigned short* __restrict__ Wh,
    const float* __restrict__ bias,
    const float* __restrict__ x,
    const float* __restrict__ lnw,
    const float* __restrict__ lnb,
    float* __restrict__ out)
{
    const int D = 512;
    __shared__ __align__(16) unsigned short As[32 * 64];    // 4KB
    __shared__ __align__(16) unsigned short Bs[512 * 64];   // 64KB
    __shared__ float psum[32][4], psq[32][4];

    int i0 = blockIdx.x << 5;
    int t = threadIdx.x;
    int lane = t & 63;
    int w = t >> 6;
    int wc = w << 7;                 // wave column base (0,128,256,384)

    int srow = t >> 3;               // 0..31
    int chunk = t & 7;
    char* Ac = (char*)As;
    char* Bc = (char*)Bs;

    f32x4 acc[2][8];
    #pragma unroll
    for (int i = 0; i < 2; ++i)
        #pragma unroll
        for (int j = 0; j < 8; ++j)
            acc[i][j] = (f32x4){0.f, 0.f, 0.f, 0.f};

    const int lane15 = lane & 15;
    const int kbyte = (lane >> 4) << 4;
    const int swa = (lane & 7) << 4;

    for (int kc = 0; kc < D; kc += 64) {
        {   // A: 32 rows of aggh
            int sc = chunk ^ (srow & 7);
            gl_lds16(aggh + (size_t)(i0 + srow) * D + kc + sc * 8, Ac + srow * 128 + chunk * 16);
        }
        #pragma unroll
        for (int q = 0; q < 16; ++q) {   // B: all 512 rows of Wh
            int row = srow + (q << 5);
            int sc = chunk ^ (row & 7);
            gl_lds16(Wh + (size_t)row * D + kc + sc * 8, Bc + row * 128 + chunk * 16);
        }
        asm volatile("s_waitcnt vmcnt(0)" ::: "memory");
        __syncthreads();
        #pragma unroll
        for (int kk = 0; kk < 2; ++kk) {
            s16x8 af[2], bg[8];
            #pragma unroll
            for (int f = 0; f < 2; ++f) {
                int ar = (f << 4) + lane15;
                af[f] = *(const s16x8*)(Ac + ar * 128 + (((kk << 6) + kbyte) ^ ((ar & 7) << 4)));
            }
            #pragma unroll
            for (int f = 0; f < 8; ++f) {
                int br = wc + (f << 4) + lane15;
                bg[f] = *(const s16x8*)(Bc + br * 128 + (((kk << 6) + kbyte) ^ swa));
            }
            #pragma unroll
            for (int fm = 0; fm < 2; ++fm)
                #pragma unroll
                for (int fn = 0; fn < 8; ++fn)
                    acc[fm][fn] = __builtin_amdgcn_mfma_f32_16x16x32_bf16(af[fm], bg[fn], acc[fm][fn], 0, 0, 0);
        }
        __syncthreads();
    }

    // epilogue: h = x + relu(acc + b)*scale, then LN over full rows
    const float scale = 0.044194173824159216f;   // 512^-0.5
    float bi[8], lw[8], lb[8];
    #pragma unroll
    for (int fn = 0; fn < 8; ++fn) {
        int colg = wc + (fn << 4) + lane15;
        bi[fn] = bias[colg];
        lw[fn] = lnw[colg];
        lb[fn] = lnb[colg];
    }
    int r0 = (lane >> 4) << 2;
    #pragma unroll
    for (int fm = 0; fm < 2; ++fm) {
        #pragma unroll
        for (int j = 0; j < 4; ++j) {
            int r = (fm << 4) + r0 + j;
            const float* xrow = x + (size_t)(i0 + r) * D;
            float s = 0.f, q = 0.f;
            #pragma unroll
            for (int fn = 0; fn < 8; ++fn) {
                int colg = wc + (fn << 4) + lane15;
                float v = fmaxf(acc[fm][fn][j] + bi[fn], 0.f) * scale + xrow[colg];
                acc[fm][fn][j] = v;
                s += v;
                q += v * v;
            }
            #pragma unroll
            for (int m = 1; m < 16; m <<= 1) {
                s += __shfl_xor(s, m);
                q += __shfl_xor(q, m);
            }
            if (lane15 == 0) { psum[r][w] = s; psq[r][w] = q; }
        }
    }
    __syncthreads();
    #pragma unroll
    for (int fm = 0; fm < 2; ++fm) {
        #pragma unroll
        for (int j = 0; j < 4; ++j) {
            int r = (fm << 4) + r0 + j;
            float s = psum[r][0] + psum[r][1] + psum[r][2] + psum[r][3];
            float q = psq[r][0] + psq[r][1] + psq[r][2] + psq[r][3];
            float mu = s * (1.f / 512.f);
            float var = q * (1.f / 512.f) - mu * mu;
            float rstd = rsqrtf(var + LN_EPS);
            float* orow = out + (size_t)(i0 + r) * D;
            #pragma unroll
            for (int fn = 0; fn < 8; ++fn) {
                int colg = wc + (fn << 4) + lane15;
                orow[colg] = lw[fn] * (acc[fm][fn][j] - mu) * rstd + lb[fn];
            }
        }
    }
}

extern "C" void kernel_launch(void* const* d_in, const int* in_sizes, int n_in,
                              void* d_out, int out_size, void* d_ws, size_t ws_size,
                              hipStream_t stream) {
    const float* x    = (const float*)d_in[0];
    const float* adj  = (const float*)d_in[1];
    const int*   pm   = (const int*)d_in[2];
    const float* W    = (const float*)d_in[3];
    const float* bias = (const float*)d_in[4];
    const float* lnw  = (const float*)d_in[5];
    const float* lnb  = (const float*)d_in[6];
    const float* ew   = (const float*)d_in[7];

    int BL = in_sizes[2];                 // B*L = 16384
    int L  = in_sizes[1] / BL;            // 2048
    int B  = BL / L;                      // 8
    int D  = in_sizes[0] / BL;            // 512

    char* ws = (char*)d_ws;
    size_t off = 0;
    float* dis   = (float*)(ws + off); off += (size_t)BL * 4;
    float* rs    = (float*)(ws + off); off += (size_t)BL * 4;
    float* rself = (float*)(ws + off); off += (size_t)BL * 4;
    unsigned short* am   = (unsigned short*)(ws + off); off += (size_t)BL * L * 2;
    unsigned short* yht  = (unsigned short*)(ws + off); off += (size_t)BL * D * 2;
    unsigned short* Wh   = (unsigned short*)(ws + off); off += (size_t)D * D * 2;
    unsigned short* aggh = (unsigned short*)(ws + off); off += (size_t)BL * D * 2;

    float* out = (float*)d_out;

    k_deg<<<BL, 256, 0, stream>>>(adj, pm, ew, dis, rs, rself, am, L);
    k_wh<<<(D * D) / 1024, 256, 0, stream>>>(W, Wh);
    k_xt<<<dim3(L / 64, D / 64, B), 256, 0, stream>>>(x, dis, yht, L, D);
    k_aggmm<<<B * (L / 128) * (D / 128), 256, 0, stream>>>(am, yht, x, rs, rself, aggh, L, D);
    k_linln<<<BL / 32, 256, 0, stream>>>(aggh, Wh, bias, x, lnw, lnb, out);
}